// Round 2
// baseline (4189.747 us; speedup 1.0000x reference)
//
#include <hip/hip_runtime.h>

// ============================================================================
// Fused 3-stage LSTM (centerline H=32 T=100, encoder H=64 T=20, decoder H=96
// T=30 + 96->2 projection) for B=131072 independent samples.
// MFMA bf16 16x16x32 with hi/lo bf16 3-term split (~fp32 precision), c in fp32
// registers. Round 2: h double-buffer -> 1 barrier/step; lo-weights read from
// global (L2-resident) instead of an 80KB LDS stage -> LDS 118.8KB -> 58.6KB
// -> 2 blocks/CU (12 waves) instead of 1 (6 waves).
// ============================================================================

#define B_TOTAL 131072
#define TB 48
#define NBLK ((B_TOTAL + TB - 1) / TB)   // 2731

typedef __attribute__((ext_vector_type(8))) short bf16x8;
typedef __attribute__((ext_vector_type(4))) float f32x4;

#define MFMA16(a, b, c) __builtin_amdgcn_mfma_f32_16x16x32_bf16((a), (b), (c), 0, 0, 0)

#ifndef __has_builtin
#define __has_builtin(x) 0
#endif
#if __has_builtin(__builtin_amdgcn_exp2f)
#define EXP2(x) __builtin_amdgcn_exp2f(x)
#else
#define EXP2(x) exp2f(x)
#endif
#if __has_builtin(__builtin_amdgcn_rcpf)
#define RCPF(x) __builtin_amdgcn_rcpf(x)
#else
#define RCPF(x) (1.0f / (x))
#endif

#define L2E 1.44269504088896340736f
#define NEG2L2E (-2.88539008177792681472f)

// ws layout (offsets in ushorts). Weights are prescaled (i,f,o rows by log2e,
// g rows by 2*log2e), decoder Wih+Whh combined, x-columns appended, split hi/lo.
#define OFF_WD_HI 0         // [384][96]
#define OFF_WD_LO 36864
#define OFF_WE_HI 73728     // [256][96]  (cols 0..63 = Whh, 64..65 = Wih, rest 0)
#define OFF_WE_LO 98304
#define OFF_WC_HI 122880    // [128][64]  (cols 0..31 = Whh, 32..33 = Wih, rest 0)
#define OFF_WC_LO 131072
#define OFF_WM_HI 139264    // [16][96]   (rows 0..1 = W_emb, rest 0)
#define OFF_WM_LO 140800
#define OFF_BIAS  142336    // floats: bd[384], be[256], bc[128], bemb[2]

__device__ __forceinline__ void split2(float f, unsigned short& hi, unsigned short& lo)
{
  unsigned int u = __float_as_uint(f);
  hi = (unsigned short)(u >> 16);
  float r = f - __uint_as_float(u & 0xFFFF0000u);   // exact residual
  lo = (unsigned short)(__float_as_uint(r) >> 16);
}

__device__ __forceinline__ bf16x8 zero8()
{
  bf16x8 z;
#pragma unroll
  for (int e = 0; e < 8; ++e) z[e] = 0;
  return z;
}

__device__ __forceinline__ f32x4 splat4(float v)
{
  f32x4 a; a[0] = v; a[1] = v; a[2] = v; a[3] = v; return a;
}

// Build the x-part A fragment: logical k=0,1 of this k-block live in lane
// group 0, elements 0,1 (same convention used for the B-side x columns).
__device__ __forceinline__ void load_x2(const float* __restrict__ base, long s, int stridef,
                                        int t, bool active, bf16x8& xhi, bf16x8& xlo)
{
  xhi = zero8(); xlo = zero8();
  if (active) {
    const float* p = base + s * (long)stridef + t * 2;
    float x0 = p[0], x1 = p[1];
    unsigned short h0, l0, h1, l1;
    split2(x0, h0, l0); split2(x1, h1, l1);
    xhi[0] = (short)h0; xhi[1] = (short)h1;
    xlo[0] = (short)l0; xlo[1] = (short)l1;
  }
}

// ---------------------------------------------------------------------------
// Prep kernel: combine/prescale/split weights into ws.
// ---------------------------------------------------------------------------
__global__ void prep_weights(
    const float* __restrict__ Wih_c, const float* __restrict__ Whh_c,
    const float* __restrict__ bih_c, const float* __restrict__ bhh_c,
    const float* __restrict__ Wih_e, const float* __restrict__ Whh_e,
    const float* __restrict__ bih_e, const float* __restrict__ bhh_e,
    const float* __restrict__ Wih_d, const float* __restrict__ Whh_d,
    const float* __restrict__ bih_d, const float* __restrict__ bhh_d,
    const float* __restrict__ W_emb, const float* __restrict__ b_emb,
    unsigned short* __restrict__ wsu)
{
  int idx = blockIdx.x * 256 + threadIdx.x;
  float* wsf = (float*)(wsu + OFF_BIAS);
  unsigned short h, l;
  if (idx < 384 * 96) {
    int j = idx / 96;
    float s = (j >= 192 && j < 288) ? 2.0f * L2E : L2E;
    float w = (Wih_d[idx] + Whh_d[idx]) * s;
    split2(w, h, l);
    wsu[OFF_WD_HI + idx] = h; wsu[OFF_WD_LO + idx] = l;
  }
  if (idx < 256 * 96) {
    int j = idx / 96, k = idx - j * 96;
    float s = (j >= 128 && j < 192) ? 2.0f * L2E : L2E;
    float w = 0.0f;
    if (k < 64) w = Whh_e[j * 64 + k] * s;
    else if (k < 66) w = Wih_e[j * 2 + (k - 64)] * s;
    split2(w, h, l);
    wsu[OFF_WE_HI + idx] = h; wsu[OFF_WE_LO + idx] = l;
  }
  if (idx < 128 * 64) {
    int j = idx / 64, k = idx - j * 64;
    float s = (j >= 64 && j < 96) ? 2.0f * L2E : L2E;
    float w = 0.0f;
    if (k < 32) w = Whh_c[j * 32 + k] * s;
    else if (k < 34) w = Wih_c[j * 2 + (k - 32)] * s;
    split2(w, h, l);
    wsu[OFF_WC_HI + idx] = h; wsu[OFF_WC_LO + idx] = l;
  }
  if (idx < 16 * 96) {
    int n = idx / 96, k = idx - n * 96;
    float w = (n < 2) ? W_emb[n * 96 + k] : 0.0f;
    split2(w, h, l);
    wsu[OFF_WM_HI + idx] = h; wsu[OFF_WM_LO + idx] = l;
  }
  if (idx < 384) {
    float s = (idx >= 192 && idx < 288) ? 2.0f * L2E : L2E;
    wsf[idx] = (bih_d[idx] + bhh_d[idx]) * s;
  }
  if (idx < 256) {
    float s = (idx >= 128 && idx < 192) ? 2.0f * L2E : L2E;
    wsf[384 + idx] = (bih_e[idx] + bhh_e[idx]) * s;
  }
  if (idx < 128) {
    float s = (idx >= 64 && idx < 96) ? 2.0f * L2E : L2E;
    wsf[640 + idx] = (bih_c[idx] + bhh_c[idx]) * s;
  }
  if (idx < 2) wsf[768 + idx] = b_emb[idx];
}

// ---------------------------------------------------------------------------
// Main fused kernel. Block = 384 threads (6 waves), TB = 48 samples.
// LDS: double-buffered h (hi/lo bf16, parity = step&1) + f32 c for phase
// transitions. Step t: read buf[t&1], write buf[t&1^1], ONE barrier.
// Lo-weight B-fragments are read from global (L2-resident) inside the loop.
// ---------------------------------------------------------------------------
__global__ __launch_bounds__(384, 3) void lstm_fused(
    const float* __restrict__ traj,
    const float* __restrict__ ctr,
    const unsigned short* __restrict__ wsu,
    float* __restrict__ out)
{
  const int tid = threadIdx.x;
  const int wid = tid >> 6;
  const int lane = tid & 63;
  const int lr = lane & 15;
  const int lg = lane >> 4;
  const int blk = blockIdx.x;

  const float* bias_d = (const float*)(wsu + OFF_BIAS);
  const float* bias_e = bias_d + 384;
  const float* bias_c = bias_d + 640;
  const float* bias_m = bias_d + 768;

  __shared__ __align__(16) unsigned short sh_hi[2][TB * 104];
  __shared__ __align__(16) unsigned short sh_lo[2][TB * 104];
  __shared__ float sc[TB * 97];

  { // zero both h buffers (h0 = 0 for all phases)
    unsigned int* p0 = (unsigned int*)sh_hi;
    unsigned int* p1 = (unsigned int*)sh_lo;
    for (int i = tid; i < 2 * TB * 104 / 2; i += 384) { p0[i] = 0u; p1[i] = 0u; }
  }
  __syncthreads();

  // ================= centerline LSTM: H=32, T=100 (h cols 64..95) ==========
  {
    const int ut = wid & 1;           // unit-tile 0..1
    const int rg = wid >> 1;          // row-tile 0..2
    const int ucol = ut * 16 + lr;    // unit 0..31
    bf16x8 Bh_hi[4], Bh_lo[4], Bx_hi[4], Bx_lo[4];
    float bias[4];
#pragma unroll
    for (int g = 0; g < 4; ++g) {
      int j = g * 32 + ucol;
      Bh_hi[g] = *(const bf16x8*)(wsu + OFF_WC_HI + j * 64 + lg * 8);
      Bh_lo[g] = *(const bf16x8*)(wsu + OFF_WC_LO + j * 64 + lg * 8);
      Bx_hi[g] = *(const bf16x8*)(wsu + OFF_WC_HI + j * 64 + 32 + lg * 8);
      Bx_lo[g] = *(const bf16x8*)(wsu + OFF_WC_LO + j * 64 + 32 + lg * 8);
      bias[g] = bias_c[j];
    }
    float cr[4];
#pragma unroll
    for (int q = 0; q < 4; ++q) cr[q] = 0.0f;
    long srow = (long)blk * TB + rg * 16 + lr;
    if (srow > B_TOTAL - 1) srow = B_TOTAL - 1;
    bf16x8 Ax_hi, Ax_lo;
    load_x2(ctr, srow, 200, 0, lg == 0, Ax_hi, Ax_lo);
    for (int t = 0; t < 100; ++t) {
      const int cur = t & 1;
      bf16x8 Ah_hi = *(const bf16x8*)&sh_hi[cur][(rg * 16 + lr) * 104 + 64 + lg * 8];
      bf16x8 Ah_lo = *(const bf16x8*)&sh_lo[cur][(rg * 16 + lr) * 104 + 64 + lg * 8];
      f32x4 acc[4];
#pragma unroll
      for (int g = 0; g < 4; ++g) {
        f32x4 a = splat4(bias[g]);
        a = MFMA16(Ah_hi, Bh_hi[g], a);
        a = MFMA16(Ah_lo, Bh_hi[g], a);
        a = MFMA16(Ah_hi, Bh_lo[g], a);
        a = MFMA16(Ax_hi, Bx_hi[g], a);
        a = MFMA16(Ax_lo, Bx_hi[g], a);
        a = MFMA16(Ax_hi, Bx_lo[g], a);
        acc[g] = a;
      }
#pragma unroll
      for (int q = 0; q < 4; ++q) {
        float ig = acc[0][q], fg = acc[1][q], gg = acc[2][q], og = acc[3][q];
        float si = RCPF(1.0f + EXP2(-ig));
        float sf = RCPF(1.0f + EXP2(-fg));
        float so = RCPF(1.0f + EXP2(-og));
        float tg = 2.0f * RCPF(1.0f + EXP2(-gg)) - 1.0f;
        float cn = sf * cr[q] + si * tg;
        cr[q] = cn;
        float tc = 2.0f * RCPF(1.0f + EXP2(cn * NEG2L2E)) - 1.0f;
        float hv = so * tc;
        unsigned short hh, hl;
        split2(hv, hh, hl);
        int r = rg * 16 + lg * 4 + q;
        sh_hi[cur ^ 1][r * 104 + 64 + ucol] = hh;
        sh_lo[cur ^ 1][r * 104 + 64 + ucol] = hl;
      }
      int tn = t < 99 ? t + 1 : 99;
      load_x2(ctr, srow, 200, tn, lg == 0, Ax_hi, Ax_lo);
      __syncthreads();   // buf[cur^1] complete for next step
    }
    // t=99 wrote buf0 -> final cent h in buf0 cols 64..95
#pragma unroll
    for (int q = 0; q < 4; ++q)
      sc[(rg * 16 + lg * 4 + q) * 97 + 64 + ucol] = cr[q];
  }
  __syncthreads();

  // ================= encoder LSTM: H=64, T=20 (h cols 0..63) ===============
  {
    const bool act = (wid < 4);
    const int ut = wid;
    const int ucol = ut * 16 + lr;
    bf16x8 Bh_hi[4][2], Bx_hi[4];
    float bias[4];
    float cr[3][4];
    long srow[3];
    if (act) {
#pragma unroll
      for (int g = 0; g < 4; ++g) {
        int j = g * 64 + ucol;
#pragma unroll
        for (int kb = 0; kb < 2; ++kb)
          Bh_hi[g][kb] = *(const bf16x8*)(wsu + OFF_WE_HI + j * 96 + kb * 32 + lg * 8);
        Bx_hi[g] = *(const bf16x8*)(wsu + OFF_WE_HI + j * 96 + 64 + lg * 8);
        bias[g] = bias_e[j];
      }
#pragma unroll
      for (int rt = 0; rt < 3; ++rt) {
#pragma unroll
        for (int q = 0; q < 4; ++q) cr[rt][q] = 0.0f;
        long s = (long)blk * TB + rt * 16 + lr;
        srow[rt] = s > B_TOTAL - 1 ? B_TOTAL - 1 : s;
      }
    }
    bf16x8 Ax_hi[3], Ax_lo[3];
    if (act) {
#pragma unroll
      for (int rt = 0; rt < 3; ++rt)
        load_x2(traj, srow[rt], 40, 0, lg == 0, Ax_hi[rt], Ax_lo[rt]);
    }
    for (int t = 0; t < 20; ++t) {
      const int cur = t & 1;
      f32x4 acc[3][4];
      if (act) {
#pragma unroll
        for (int rt = 0; rt < 3; ++rt)
#pragma unroll
          for (int g = 0; g < 4; ++g) acc[rt][g] = splat4(bias[g]);
#pragma unroll
        for (int kb = 0; kb < 2; ++kb) {
          bf16x8 ahi[3], alo[3];
#pragma unroll
          for (int rt = 0; rt < 3; ++rt) {
            ahi[rt] = *(const bf16x8*)&sh_hi[cur][(rt * 16 + lr) * 104 + kb * 32 + lg * 8];
            alo[rt] = *(const bf16x8*)&sh_lo[cur][(rt * 16 + lr) * 104 + kb * 32 + lg * 8];
          }
#pragma unroll
          for (int g = 0; g < 4; ++g) {
            bf16x8 blo = *(const bf16x8*)(wsu + OFF_WE_LO + (g * 64 + ucol) * 96 + kb * 32 + lg * 8);
#pragma unroll
            for (int rt = 0; rt < 3; ++rt) {
              acc[rt][g] = MFMA16(ahi[rt], Bh_hi[g][kb], acc[rt][g]);
              acc[rt][g] = MFMA16(alo[rt], Bh_hi[g][kb], acc[rt][g]);
              acc[rt][g] = MFMA16(ahi[rt], blo, acc[rt][g]);
            }
          }
        }
#pragma unroll
        for (int g = 0; g < 4; ++g) {   // x contribution (k-block 2)
          bf16x8 blox = *(const bf16x8*)(wsu + OFF_WE_LO + (g * 64 + ucol) * 96 + 64 + lg * 8);
#pragma unroll
          for (int rt = 0; rt < 3; ++rt) {
            acc[rt][g] = MFMA16(Ax_hi[rt], Bx_hi[g], acc[rt][g]);
            acc[rt][g] = MFMA16(Ax_lo[rt], Bx_hi[g], acc[rt][g]);
            acc[rt][g] = MFMA16(Ax_hi[rt], blox, acc[rt][g]);
          }
        }
#pragma unroll
        for (int rt = 0; rt < 3; ++rt) {
#pragma unroll
          for (int q = 0; q < 4; ++q) {
            float ig = acc[rt][0][q], fg = acc[rt][1][q], gg = acc[rt][2][q], og = acc[rt][3][q];
            float si = RCPF(1.0f + EXP2(-ig));
            float sf = RCPF(1.0f + EXP2(-fg));
            float so = RCPF(1.0f + EXP2(-og));
            float tg = 2.0f * RCPF(1.0f + EXP2(-gg)) - 1.0f;
            float cn = sf * cr[rt][q] + si * tg;
            cr[rt][q] = cn;
            float tc = 2.0f * RCPF(1.0f + EXP2(cn * NEG2L2E)) - 1.0f;
            float hv = so * tc;
            unsigned short hh, hl;
            split2(hv, hh, hl);
            int r = rt * 16 + lg * 4 + q;
            sh_hi[cur ^ 1][r * 104 + ucol] = hh;
            sh_lo[cur ^ 1][r * 104 + ucol] = hl;
          }
        }
        int tn = t < 19 ? t + 1 : 19;
#pragma unroll
        for (int rt = 0; rt < 3; ++rt)
          load_x2(traj, srow[rt], 40, tn, lg == 0, Ax_hi[rt], Ax_lo[rt]);
      }
      __syncthreads();
    }
    // t=19 wrote buf0 -> buf0 now holds [enc_h | cent_h] = decoder h0
    if (act) {
#pragma unroll
      for (int rt = 0; rt < 3; ++rt)
#pragma unroll
        for (int q = 0; q < 4; ++q)
          sc[(rt * 16 + lg * 4 + q) * 97 + ucol] = cr[rt][q];
    }
  }
  __syncthreads();

  // ================= decoder LSTM: H=96, T=30 + projection =================
  {
    const int ut = wid;               // 0..5
    const int ucol = ut * 16 + lr;    // unit 0..95
    bf16x8 Bh_hi[4][3];
    float bias[4];
    float cr[3][4];
#pragma unroll
    for (int g = 0; g < 4; ++g) {
      int j = g * 96 + ucol;
#pragma unroll
      for (int kb = 0; kb < 3; ++kb)
        Bh_hi[g][kb] = *(const bf16x8*)(wsu + OFF_WD_HI + j * 96 + kb * 32 + lg * 8);
      bias[g] = bias_d[j];
    }
    float pbias = (lr < 2) ? bias_m[lr] : 0.0f;
#pragma unroll
    for (int rt = 0; rt < 3; ++rt)      // c0 = [c_enc | c_cent]
#pragma unroll
      for (int q = 0; q < 4; ++q)
        cr[rt][q] = sc[(rt * 16 + lg * 4 + q) * 97 + ucol];
    for (int t = 0; t < 30; ++t) {
      const int cur = t & 1;
      f32x4 acc[3][4];
#pragma unroll
      for (int rt = 0; rt < 3; ++rt)
#pragma unroll
        for (int g = 0; g < 4; ++g) acc[rt][g] = splat4(bias[g]);
#pragma unroll
      for (int kb = 0; kb < 3; ++kb) {
        bf16x8 ahi[3], alo[3];
#pragma unroll
        for (int rt = 0; rt < 3; ++rt) {
          ahi[rt] = *(const bf16x8*)&sh_hi[cur][(rt * 16 + lr) * 104 + kb * 32 + lg * 8];
          alo[rt] = *(const bf16x8*)&sh_lo[cur][(rt * 16 + lr) * 104 + kb * 32 + lg * 8];
        }
#pragma unroll
        for (int g = 0; g < 4; ++g) {
          bf16x8 blo = *(const bf16x8*)(wsu + OFF_WD_LO + (g * 96 + ucol) * 96 + kb * 32 + lg * 8);
#pragma unroll
          for (int rt = 0; rt < 3; ++rt) {
            acc[rt][g] = MFMA16(ahi[rt], Bh_hi[g][kb], acc[rt][g]);
            acc[rt][g] = MFMA16(alo[rt], Bh_hi[g][kb], acc[rt][g]);
            acc[rt][g] = MFMA16(ahi[rt], blo, acc[rt][g]);
          }
        }
      }
#pragma unroll
      for (int rt = 0; rt < 3; ++rt) {
#pragma unroll
        for (int q = 0; q < 4; ++q) {
          float ig = acc[rt][0][q], fg = acc[rt][1][q], gg = acc[rt][2][q], og = acc[rt][3][q];
          float si = RCPF(1.0f + EXP2(-ig));
          float sf = RCPF(1.0f + EXP2(-fg));
          float so = RCPF(1.0f + EXP2(-og));
          float tg = 2.0f * RCPF(1.0f + EXP2(-gg)) - 1.0f;
          float cn = sf * cr[rt][q] + si * tg;
          cr[rt][q] = cn;
          float tc = 2.0f * RCPF(1.0f + EXP2(cn * NEG2L2E)) - 1.0f;
          float hv = so * tc;
          unsigned short hh, hl;
          split2(hv, hh, hl);
          int r = rt * 16 + lg * 4 + q;
          sh_hi[cur ^ 1][r * 104 + ucol] = hh;
          sh_lo[cur ^ 1][r * 104 + ucol] = hl;
        }
      }
      __syncthreads();   // buf[cur^1] complete (used by projection + next step)
      // projection: pos = h_new @ W_emb^T + b_emb ; waves 0..2, rt = wid
      if (wid < 3) {
        f32x4 ap = splat4(pbias);
#pragma unroll
        for (int kb = 0; kb < 3; ++kb) {
          bf16x8 ahi = *(const bf16x8*)&sh_hi[cur ^ 1][(wid * 16 + lr) * 104 + kb * 32 + lg * 8];
          bf16x8 alo = *(const bf16x8*)&sh_lo[cur ^ 1][(wid * 16 + lr) * 104 + kb * 32 + lg * 8];
          bf16x8 bmh = *(const bf16x8*)(wsu + OFF_WM_HI + lr * 96 + kb * 32 + lg * 8);
          bf16x8 bml = *(const bf16x8*)(wsu + OFF_WM_LO + lr * 96 + kb * 32 + lg * 8);
          ap = MFMA16(ahi, bmh, ap);
          ap = MFMA16(alo, bmh, ap);
          ap = MFMA16(ahi, bml, ap);
        }
        if (lr < 2) {
#pragma unroll
          for (int q = 0; q < 4; ++q) {
            long s = (long)blk * TB + wid * 16 + lg * 4 + q;
            if (s < B_TOTAL) out[s * 60 + t * 2 + lr] = ap[q];
          }
        }
      }
    }
  }
}

extern "C" void kernel_launch(void* const* d_in, const int* in_sizes, int n_in,
                              void* d_out, int out_size, void* d_ws, size_t ws_size,
                              hipStream_t stream)
{
  if (ws_size < 287752) return;   // need ~288 KB of scratch for prepped weights
  const float* traj = (const float*)d_in[0];
  const float* ctr  = (const float*)d_in[1];
  prep_weights<<<144, 256, 0, stream>>>(
      (const float*)d_in[2],  (const float*)d_in[3],  (const float*)d_in[4],  (const float*)d_in[5],
      (const float*)d_in[6],  (const float*)d_in[7],  (const float*)d_in[8],  (const float*)d_in[9],
      (const float*)d_in[10], (const float*)d_in[11], (const float*)d_in[12], (const float*)d_in[13],
      (const float*)d_in[14], (const float*)d_in[15],
      (unsigned short*)d_ws);
  lstm_fused<<<NBLK, 384, 0, stream>>>(traj, ctr, (const unsigned short*)d_ws, (float*)d_out);
}

// Round 3
// 3437.249 us; speedup vs baseline: 1.2189x; 1.2189x over previous
//
#include <hip/hip_runtime.h>

// ============================================================================
// Fused 3-stage LSTM (centerline H=32 T=100, encoder H=64 T=20, decoder H=96
// T=30 + 96->2 projection) for B=131072 independent samples.
// MFMA bf16 16x16x32 with hi/lo bf16 3-term split (~fp32 precision), c in fp32
// registers. Round 3: h double-buffer (1 barrier/step) kept; enc/dec weight
// B-fragments (hi AND lo) are loaded from global (L2-resident) inside the
// step loop, with an opaque offset to defeat LICM re-hoisting -> peak register
// demand ~120 unified regs -> no spill at launch_bounds(384,3) -> 2 blocks/CU.
// Round-2 failure was a register spill (WRITE_SIZE 845MB = scratch stores).
// ============================================================================

#define B_TOTAL 131072
#define TB 48
#define NBLK ((B_TOTAL + TB - 1) / TB)   // 2731

typedef __attribute__((ext_vector_type(8))) short bf16x8;
typedef __attribute__((ext_vector_type(4))) float f32x4;

#define MFMA16(a, b, c) __builtin_amdgcn_mfma_f32_16x16x32_bf16((a), (b), (c), 0, 0, 0)

#ifndef __has_builtin
#define __has_builtin(x) 0
#endif
#if __has_builtin(__builtin_amdgcn_exp2f)
#define EXP2(x) __builtin_amdgcn_exp2f(x)
#else
#define EXP2(x) exp2f(x)
#endif
#if __has_builtin(__builtin_amdgcn_rcpf)
#define RCPF(x) __builtin_amdgcn_rcpf(x)
#else
#define RCPF(x) (1.0f / (x))
#endif

#define L2E 1.44269504088896340736f
#define NEG2L2E (-2.88539008177792681472f)

// ws layout (offsets in ushorts). Weights are prescaled (i,f,o rows by log2e,
// g rows by 2*log2e), decoder Wih+Whh combined, x-columns appended, split hi/lo.
#define OFF_WD_HI 0         // [384][96]
#define OFF_WD_LO 36864
#define OFF_WE_HI 73728     // [256][96]  (cols 0..63 = Whh, 64..65 = Wih, rest 0)
#define OFF_WE_LO 98304
#define OFF_WC_HI 122880    // [128][64]  (cols 0..31 = Whh, 32..33 = Wih, rest 0)
#define OFF_WC_LO 131072
#define OFF_WM_HI 139264    // [16][96]   (rows 0..1 = W_emb, rest 0)
#define OFF_WM_LO 140800
#define OFF_BIAS  142336    // floats: bd[384], be[256], bc[128], bemb[2]

__device__ __forceinline__ void split2(float f, unsigned short& hi, unsigned short& lo)
{
  unsigned int u = __float_as_uint(f);
  hi = (unsigned short)(u >> 16);
  float r = f - __uint_as_float(u & 0xFFFF0000u);   // exact residual
  lo = (unsigned short)(__float_as_uint(r) >> 16);
}

__device__ __forceinline__ bf16x8 zero8()
{
  bf16x8 z;
#pragma unroll
  for (int e = 0; e < 8; ++e) z[e] = 0;
  return z;
}

__device__ __forceinline__ f32x4 splat4(float v)
{
  f32x4 a; a[0] = v; a[1] = v; a[2] = v; a[3] = v; return a;
}

// Build the x-part A fragment: logical k=0,1 of this k-block live in lane
// group 0, elements 0,1 (same convention used for the B-side x columns).
__device__ __forceinline__ void load_x2(const float* __restrict__ base, long s, int stridef,
                                        int t, bool active, bf16x8& xhi, bf16x8& xlo)
{
  xhi = zero8(); xlo = zero8();
  if (active) {
    const float* p = base + s * (long)stridef + t * 2;
    float x0 = p[0], x1 = p[1];
    unsigned short h0, l0, h1, l1;
    split2(x0, h0, l0); split2(x1, h1, l1);
    xhi[0] = (short)h0; xhi[1] = (short)h1;
    xlo[0] = (short)l0; xlo[1] = (short)l1;
  }
}

// ---------------------------------------------------------------------------
// Prep kernel: combine/prescale/split weights into ws.
// ---------------------------------------------------------------------------
__global__ void prep_weights(
    const float* __restrict__ Wih_c, const float* __restrict__ Whh_c,
    const float* __restrict__ bih_c, const float* __restrict__ bhh_c,
    const float* __restrict__ Wih_e, const float* __restrict__ Whh_e,
    const float* __restrict__ bih_e, const float* __restrict__ bhh_e,
    const float* __restrict__ Wih_d, const float* __restrict__ Whh_d,
    const float* __restrict__ bih_d, const float* __restrict__ bhh_d,
    const float* __restrict__ W_emb, const float* __restrict__ b_emb,
    unsigned short* __restrict__ wsu)
{
  int idx = blockIdx.x * 256 + threadIdx.x;
  float* wsf = (float*)(wsu + OFF_BIAS);
  unsigned short h, l;
  if (idx < 384 * 96) {
    int j = idx / 96;
    float s = (j >= 192 && j < 288) ? 2.0f * L2E : L2E;
    float w = (Wih_d[idx] + Whh_d[idx]) * s;
    split2(w, h, l);
    wsu[OFF_WD_HI + idx] = h; wsu[OFF_WD_LO + idx] = l;
  }
  if (idx < 256 * 96) {
    int j = idx / 96, k = idx - j * 96;
    float s = (j >= 128 && j < 192) ? 2.0f * L2E : L2E;
    float w = 0.0f;
    if (k < 64) w = Whh_e[j * 64 + k] * s;
    else if (k < 66) w = Wih_e[j * 2 + (k - 64)] * s;
    split2(w, h, l);
    wsu[OFF_WE_HI + idx] = h; wsu[OFF_WE_LO + idx] = l;
  }
  if (idx < 128 * 64) {
    int j = idx / 64, k = idx - j * 64;
    float s = (j >= 64 && j < 96) ? 2.0f * L2E : L2E;
    float w = 0.0f;
    if (k < 32) w = Whh_c[j * 32 + k] * s;
    else if (k < 34) w = Wih_c[j * 2 + (k - 32)] * s;
    split2(w, h, l);
    wsu[OFF_WC_HI + idx] = h; wsu[OFF_WC_LO + idx] = l;
  }
  if (idx < 16 * 96) {
    int n = idx / 96, k = idx - n * 96;
    float w = (n < 2) ? W_emb[n * 96 + k] : 0.0f;
    split2(w, h, l);
    wsu[OFF_WM_HI + idx] = h; wsu[OFF_WM_LO + idx] = l;
  }
  if (idx < 384) {
    float s = (idx >= 192 && idx < 288) ? 2.0f * L2E : L2E;
    wsf[idx] = (bih_d[idx] + bhh_d[idx]) * s;
  }
  if (idx < 256) {
    float s = (idx >= 128 && idx < 192) ? 2.0f * L2E : L2E;
    wsf[384 + idx] = (bih_e[idx] + bhh_e[idx]) * s;
  }
  if (idx < 128) {
    float s = (idx >= 64 && idx < 96) ? 2.0f * L2E : L2E;
    wsf[640 + idx] = (bih_c[idx] + bhh_c[idx]) * s;
  }
  if (idx < 2) wsf[768 + idx] = b_emb[idx];
}

// ---------------------------------------------------------------------------
// Main fused kernel. Block = 384 threads (6 waves), TB = 48 samples.
// LDS: double-buffered h (hi/lo bf16, parity = step&1) + f32 c for phase
// transitions. Step t: read buf[t&1], write buf[t&1^1], ONE barrier.
// Enc/dec weight fragments (hi+lo) are read from global (L2-resident) inside
// the loop; `tofs` is an opaque 0 that prevents LICM from hoisting them.
// ---------------------------------------------------------------------------
__global__ __launch_bounds__(384, 3) void lstm_fused(
    const float* __restrict__ traj,
    const float* __restrict__ ctr,
    const unsigned short* __restrict__ wsu,
    float* __restrict__ out)
{
  const int tid = threadIdx.x;
  const int wid = tid >> 6;
  const int lane = tid & 63;
  const int lr = lane & 15;
  const int lg = lane >> 4;
  const int blk = blockIdx.x;

  const float* bias_d = (const float*)(wsu + OFF_BIAS);
  const float* bias_e = bias_d + 384;
  const float* bias_c = bias_d + 640;
  const float* bias_m = bias_d + 768;

  __shared__ __align__(16) unsigned short sh_hi[2][TB * 104];
  __shared__ __align__(16) unsigned short sh_lo[2][TB * 104];
  __shared__ float sc[TB * 97];

  { // zero both h buffers (h0 = 0 for all phases)
    unsigned int* p0 = (unsigned int*)sh_hi;
    unsigned int* p1 = (unsigned int*)sh_lo;
    for (int i = tid; i < 2 * TB * 104 / 2; i += 384) { p0[i] = 0u; p1[i] = 0u; }
  }
  __syncthreads();

  // ================= centerline LSTM: H=32, T=100 (h cols 64..95) ==========
  // Lightest B set (64 VGPRs) and longest phase: keep weights in registers.
  {
    const int ut = wid & 1;           // unit-tile 0..1
    const int rg = wid >> 1;          // row-tile 0..2
    const int ucol = ut * 16 + lr;    // unit 0..31
    bf16x8 Bh_hi[4], Bh_lo[4], Bx_hi[4], Bx_lo[4];
    float bias[4];
#pragma unroll
    for (int g = 0; g < 4; ++g) {
      int j = g * 32 + ucol;
      Bh_hi[g] = *(const bf16x8*)(wsu + OFF_WC_HI + j * 64 + lg * 8);
      Bh_lo[g] = *(const bf16x8*)(wsu + OFF_WC_LO + j * 64 + lg * 8);
      Bx_hi[g] = *(const bf16x8*)(wsu + OFF_WC_HI + j * 64 + 32 + lg * 8);
      Bx_lo[g] = *(const bf16x8*)(wsu + OFF_WC_LO + j * 64 + 32 + lg * 8);
      bias[g] = bias_c[j];
    }
    float cr[4];
#pragma unroll
    for (int q = 0; q < 4; ++q) cr[q] = 0.0f;
    long srow = (long)blk * TB + rg * 16 + lr;
    if (srow > B_TOTAL - 1) srow = B_TOTAL - 1;
    bf16x8 Ax_hi, Ax_lo;
    load_x2(ctr, srow, 200, 0, lg == 0, Ax_hi, Ax_lo);
    for (int t = 0; t < 100; ++t) {
      const int cur = t & 1;
      bf16x8 Ah_hi = *(const bf16x8*)&sh_hi[cur][(rg * 16 + lr) * 104 + 64 + lg * 8];
      bf16x8 Ah_lo = *(const bf16x8*)&sh_lo[cur][(rg * 16 + lr) * 104 + 64 + lg * 8];
      f32x4 acc[4];
#pragma unroll
      for (int g = 0; g < 4; ++g) {
        f32x4 a = splat4(bias[g]);
        a = MFMA16(Ah_hi, Bh_hi[g], a);
        a = MFMA16(Ah_lo, Bh_hi[g], a);
        a = MFMA16(Ah_hi, Bh_lo[g], a);
        a = MFMA16(Ax_hi, Bx_hi[g], a);
        a = MFMA16(Ax_lo, Bx_hi[g], a);
        a = MFMA16(Ax_hi, Bx_lo[g], a);
        acc[g] = a;
      }
#pragma unroll
      for (int q = 0; q < 4; ++q) {
        float ig = acc[0][q], fg = acc[1][q], gg = acc[2][q], og = acc[3][q];
        float si = RCPF(1.0f + EXP2(-ig));
        float sf = RCPF(1.0f + EXP2(-fg));
        float so = RCPF(1.0f + EXP2(-og));
        float tg = 2.0f * RCPF(1.0f + EXP2(-gg)) - 1.0f;
        float cn = sf * cr[q] + si * tg;
        cr[q] = cn;
        float tc = 2.0f * RCPF(1.0f + EXP2(cn * NEG2L2E)) - 1.0f;
        float hv = so * tc;
        unsigned short hh, hl;
        split2(hv, hh, hl);
        int r = rg * 16 + lg * 4 + q;
        sh_hi[cur ^ 1][r * 104 + 64 + ucol] = hh;
        sh_lo[cur ^ 1][r * 104 + 64 + ucol] = hl;
      }
      int tn = t < 99 ? t + 1 : 99;
      load_x2(ctr, srow, 200, tn, lg == 0, Ax_hi, Ax_lo);
      __syncthreads();   // buf[cur^1] complete for next step
    }
    // t=99 wrote buf0 -> final cent h in buf0 cols 64..95
#pragma unroll
    for (int q = 0; q < 4; ++q)
      sc[(rg * 16 + lg * 4 + q) * 97 + 64 + ucol] = cr[q];
  }
  __syncthreads();

  // ================= encoder LSTM: H=64, T=20 (h cols 0..63) ===============
  {
    const bool act = (wid < 4);
    const int ut = wid;
    const int ucol = ut * 16 + lr;
    float bias[4];
    float cr[3][4];
    long srow[3];
    if (act) {
#pragma unroll
      for (int g = 0; g < 4; ++g) bias[g] = bias_e[g * 64 + ucol];
#pragma unroll
      for (int rt = 0; rt < 3; ++rt) {
#pragma unroll
        for (int q = 0; q < 4; ++q) cr[rt][q] = 0.0f;
        long s = (long)blk * TB + rt * 16 + lr;
        srow[rt] = s > B_TOTAL - 1 ? B_TOTAL - 1 : s;
      }
    }
    bf16x8 Ax_hi[3], Ax_lo[3];
    if (act) {
#pragma unroll
      for (int rt = 0; rt < 3; ++rt)
        load_x2(traj, srow[rt], 40, 0, lg == 0, Ax_hi[rt], Ax_lo[rt]);
    }
    for (int t = 0; t < 20; ++t) {
      const int cur = t & 1;
      int tofs = 0;
      asm volatile("" : "+v"(tofs));   // opaque 0: keep B loads in-loop
      f32x4 acc[3][4];
      if (act) {
#pragma unroll
        for (int rt = 0; rt < 3; ++rt)
#pragma unroll
          for (int g = 0; g < 4; ++g) acc[rt][g] = splat4(bias[g]);
#pragma unroll
        for (int kb = 0; kb < 2; ++kb) {
          bf16x8 ahi[3], alo[3];
#pragma unroll
          for (int rt = 0; rt < 3; ++rt) {
            ahi[rt] = *(const bf16x8*)&sh_hi[cur][(rt * 16 + lr) * 104 + kb * 32 + lg * 8];
            alo[rt] = *(const bf16x8*)&sh_lo[cur][(rt * 16 + lr) * 104 + kb * 32 + lg * 8];
          }
#pragma unroll
          for (int g = 0; g < 4; ++g) {
            int bo = (g * 64 + ucol) * 96 + kb * 32 + lg * 8 + tofs;
            bf16x8 bhi = *(const bf16x8*)(wsu + OFF_WE_HI + bo);
            bf16x8 blo = *(const bf16x8*)(wsu + OFF_WE_LO + bo);
#pragma unroll
            for (int rt = 0; rt < 3; ++rt) {
              acc[rt][g] = MFMA16(ahi[rt], bhi, acc[rt][g]);
              acc[rt][g] = MFMA16(alo[rt], bhi, acc[rt][g]);
              acc[rt][g] = MFMA16(ahi[rt], blo, acc[rt][g]);
            }
          }
        }
#pragma unroll
        for (int g = 0; g < 4; ++g) {   // x contribution (k-block 2)
          int bo = (g * 64 + ucol) * 96 + 64 + lg * 8 + tofs;
          bf16x8 bxh = *(const bf16x8*)(wsu + OFF_WE_HI + bo);
          bf16x8 bxl = *(const bf16x8*)(wsu + OFF_WE_LO + bo);
#pragma unroll
          for (int rt = 0; rt < 3; ++rt) {
            acc[rt][g] = MFMA16(Ax_hi[rt], bxh, acc[rt][g]);
            acc[rt][g] = MFMA16(Ax_lo[rt], bxh, acc[rt][g]);
            acc[rt][g] = MFMA16(Ax_hi[rt], bxl, acc[rt][g]);
          }
        }
#pragma unroll
        for (int rt = 0; rt < 3; ++rt) {
#pragma unroll
          for (int q = 0; q < 4; ++q) {
            float ig = acc[rt][0][q], fg = acc[rt][1][q], gg = acc[rt][2][q], og = acc[rt][3][q];
            float si = RCPF(1.0f + EXP2(-ig));
            float sf = RCPF(1.0f + EXP2(-fg));
            float so = RCPF(1.0f + EXP2(-og));
            float tg = 2.0f * RCPF(1.0f + EXP2(-gg)) - 1.0f;
            float cn = sf * cr[rt][q] + si * tg;
            cr[rt][q] = cn;
            float tc = 2.0f * RCPF(1.0f + EXP2(cn * NEG2L2E)) - 1.0f;
            float hv = so * tc;
            unsigned short hh, hl;
            split2(hv, hh, hl);
            int r = rt * 16 + lg * 4 + q;
            sh_hi[cur ^ 1][r * 104 + ucol] = hh;
            sh_lo[cur ^ 1][r * 104 + ucol] = hl;
          }
        }
        int tn = t < 19 ? t + 1 : 19;
#pragma unroll
        for (int rt = 0; rt < 3; ++rt)
          load_x2(traj, srow[rt], 40, tn, lg == 0, Ax_hi[rt], Ax_lo[rt]);
      }
      __syncthreads();
    }
    // t=19 wrote buf0 -> buf0 now holds [enc_h | cent_h] = decoder h0
    if (act) {
#pragma unroll
      for (int rt = 0; rt < 3; ++rt)
#pragma unroll
        for (int q = 0; q < 4; ++q)
          sc[(rt * 16 + lg * 4 + q) * 97 + ucol] = cr[rt][q];
    }
  }
  __syncthreads();

  // ================= decoder LSTM: H=96, T=30 + projection =================
  {
    const int ut = wid;               // 0..5
    const int ucol = ut * 16 + lr;    // unit 0..95
    float bias[4];
    float cr[3][4];
#pragma unroll
    for (int g = 0; g < 4; ++g) bias[g] = bias_d[g * 96 + ucol];
    float pbias = (lr < 2) ? bias_m[lr] : 0.0f;
#pragma unroll
    for (int rt = 0; rt < 3; ++rt)      // c0 = [c_enc | c_cent]
#pragma unroll
      for (int q = 0; q < 4; ++q)
        cr[rt][q] = sc[(rt * 16 + lg * 4 + q) * 97 + ucol];
    for (int t = 0; t < 30; ++t) {
      const int cur = t & 1;
      int tofs = 0;
      asm volatile("" : "+v"(tofs));   // opaque 0: keep B loads in-loop
      f32x4 acc[3][4];
#pragma unroll
      for (int rt = 0; rt < 3; ++rt)
#pragma unroll
        for (int g = 0; g < 4; ++g) acc[rt][g] = splat4(bias[g]);
#pragma unroll
      for (int kb = 0; kb < 3; ++kb) {
        bf16x8 ahi[3], alo[3];
#pragma unroll
        for (int rt = 0; rt < 3; ++rt) {
          ahi[rt] = *(const bf16x8*)&sh_hi[cur][(rt * 16 + lr) * 104 + kb * 32 + lg * 8];
          alo[rt] = *(const bf16x8*)&sh_lo[cur][(rt * 16 + lr) * 104 + kb * 32 + lg * 8];
        }
#pragma unroll
        for (int g = 0; g < 4; ++g) {
          int bo = (g * 96 + ucol) * 96 + kb * 32 + lg * 8 + tofs;
          bf16x8 bhi = *(const bf16x8*)(wsu + OFF_WD_HI + bo);
          bf16x8 blo = *(const bf16x8*)(wsu + OFF_WD_LO + bo);
#pragma unroll
          for (int rt = 0; rt < 3; ++rt) {
            acc[rt][g] = MFMA16(ahi[rt], bhi, acc[rt][g]);
            acc[rt][g] = MFMA16(alo[rt], bhi, acc[rt][g]);
            acc[rt][g] = MFMA16(ahi[rt], blo, acc[rt][g]);
          }
        }
      }
#pragma unroll
      for (int rt = 0; rt < 3; ++rt) {
#pragma unroll
        for (int q = 0; q < 4; ++q) {
          float ig = acc[rt][0][q], fg = acc[rt][1][q], gg = acc[rt][2][q], og = acc[rt][3][q];
          float si = RCPF(1.0f + EXP2(-ig));
          float sf = RCPF(1.0f + EXP2(-fg));
          float so = RCPF(1.0f + EXP2(-og));
          float tg = 2.0f * RCPF(1.0f + EXP2(-gg)) - 1.0f;
          float cn = sf * cr[rt][q] + si * tg;
          cr[rt][q] = cn;
          float tc = 2.0f * RCPF(1.0f + EXP2(cn * NEG2L2E)) - 1.0f;
          float hv = so * tc;
          unsigned short hh, hl;
          split2(hv, hh, hl);
          int r = rt * 16 + lg * 4 + q;
          sh_hi[cur ^ 1][r * 104 + ucol] = hh;
          sh_lo[cur ^ 1][r * 104 + ucol] = hl;
        }
      }
      __syncthreads();   // buf[cur^1] complete (used by projection + next step)
      // projection: pos = h_new @ W_emb^T + b_emb ; waves 0..2, rt = wid
      if (wid < 3) {
        f32x4 ap = splat4(pbias);
#pragma unroll
        for (int kb = 0; kb < 3; ++kb) {
          bf16x8 ahi = *(const bf16x8*)&sh_hi[cur ^ 1][(wid * 16 + lr) * 104 + kb * 32 + lg * 8];
          bf16x8 alo = *(const bf16x8*)&sh_lo[cur ^ 1][(wid * 16 + lr) * 104 + kb * 32 + lg * 8];
          int mo = lr * 96 + kb * 32 + lg * 8 + tofs;
          bf16x8 bmh = *(const bf16x8*)(wsu + OFF_WM_HI + mo);
          bf16x8 bml = *(const bf16x8*)(wsu + OFF_WM_LO + mo);
          ap = MFMA16(ahi, bmh, ap);
          ap = MFMA16(alo, bmh, ap);
          ap = MFMA16(ahi, bml, ap);
        }
        if (lr < 2) {
#pragma unroll
          for (int q = 0; q < 4; ++q) {
            long s = (long)blk * TB + wid * 16 + lg * 4 + q;
            if (s < B_TOTAL) out[s * 60 + t * 2 + lr] = ap[q];
          }
        }
      }
    }
  }
}

extern "C" void kernel_launch(void* const* d_in, const int* in_sizes, int n_in,
                              void* d_out, int out_size, void* d_ws, size_t ws_size,
                              hipStream_t stream)
{
  if (ws_size < 287752) return;   // need ~288 KB of scratch for prepped weights
  const float* traj = (const float*)d_in[0];
  const float* ctr  = (const float*)d_in[1];
  prep_weights<<<144, 256, 0, stream>>>(
      (const float*)d_in[2],  (const float*)d_in[3],  (const float*)d_in[4],  (const float*)d_in[5],
      (const float*)d_in[6],  (const float*)d_in[7],  (const float*)d_in[8],  (const float*)d_in[9],
      (const float*)d_in[10], (const float*)d_in[11], (const float*)d_in[12], (const float*)d_in[13],
      (const float*)d_in[14], (const float*)d_in[15],
      (unsigned short*)d_ws);
  lstm_fused<<<NBLK, 384, 0, stream>>>(traj, ctr, (const unsigned short*)d_ws, (float*)d_out);
}

// Round 4
// 2726.136 us; speedup vs baseline: 1.5369x; 1.2609x over previous
//
#include <hip/hip_runtime.h>

// ============================================================================
// Fused 3-stage LSTM (centerline H=32 T=100, encoder H=64 T=20, decoder H=96
// T=30 + 96->2 projection) for B=131072 independent samples.
// Round 4: 768 threads / 12 waves / TB=96 (3 waves/SIMD balanced, half the
// serial block-passes per CU); raw s_barrier (lgkmcnt-only wait) so global
// prefetches are NOT drained at barriers; x prefetched 1 float4 (2 steps)
// ahead with x2-unrolled loops (static buffer parity); LDS = h double-buffer
// only (79.9KB) -- c phase-handoff stashed as split-bf16 in the stale buffer.
// Weight-hi in registers, weight-lo from L2 in-loop (opaque offset vs LICM).
// ============================================================================

#define B_TOTAL 131072
#define TB 96
#define NBLK ((B_TOTAL + TB - 1) / TB)   // 1366
#define S 104                             // LDS row stride in shorts

typedef __attribute__((ext_vector_type(8))) short bf16x8;
typedef __attribute__((ext_vector_type(4))) float f32x4;

#define MFMA16(a, b, c) __builtin_amdgcn_mfma_f32_16x16x32_bf16((a), (b), (c), 0, 0, 0)

#ifndef __has_builtin
#define __has_builtin(x) 0
#endif
#if __has_builtin(__builtin_amdgcn_exp2f)
#define EXP2(x) __builtin_amdgcn_exp2f(x)
#else
#define EXP2(x) exp2f(x)
#endif
#if __has_builtin(__builtin_amdgcn_rcpf)
#define RCPF(x) __builtin_amdgcn_rcpf(x)
#else
#define RCPF(x) (1.0f / (x))
#endif

#define L2E 1.44269504088896340736f
#define NEG2L2E (-2.88539008177792681472f)

// ws layout (offsets in ushorts). Weights prescaled (i,f,o rows by log2e,
// g rows by 2*log2e), decoder Wih+Whh combined, x-columns appended, hi/lo split.
#define OFF_WD_HI 0         // [384][96]
#define OFF_WD_LO 36864
#define OFF_WE_HI 73728     // [256][96]  (cols 0..63 = Whh, 64..65 = Wih, rest 0)
#define OFF_WE_LO 98304
#define OFF_WC_HI 122880    // [128][64]  (cols 0..31 = Whh, 32..33 = Wih, rest 0)
#define OFF_WC_LO 131072
#define OFF_WM_HI 139264    // [16][96]   (rows 0..1 = W_emb, rest 0)
#define OFF_WM_LO 140800
#define OFF_BIAS  142336    // floats: bd[384], be[256], bc[128], bemb[2]

__device__ __forceinline__ void split2(float f, unsigned short& hi, unsigned short& lo)
{
  unsigned int u = __float_as_uint(f);
  hi = (unsigned short)(u >> 16);
  float r = f - __uint_as_float(u & 0xFFFF0000u);   // exact residual
  lo = (unsigned short)(__float_as_uint(r) >> 16);
}

__device__ __forceinline__ bf16x8 zero8()
{
  bf16x8 z;
#pragma unroll
  for (int e = 0; e < 8; ++e) z[e] = 0;
  return z;
}

__device__ __forceinline__ f32x4 splat4(float v)
{
  f32x4 a; a[0] = v; a[1] = v; a[2] = v; a[3] = v; return a;
}

// Raw step barrier: wait LDS ops only; global reg-loads stay in flight.
#define STEP_BARRIER() asm volatile("s_waitcnt lgkmcnt(0)\n\ts_barrier" ::: "memory")

// Per-(sample,unit) LSTM update + h write (split bf16) to LDS buffer WRB.
#define ACTIVATE(IG, FG, GG, OG, CREF, WIDX, WRB) do {                        \
    float si_ = RCPF(1.0f + EXP2(-(IG)));                                     \
    float sf_ = RCPF(1.0f + EXP2(-(FG)));                                     \
    float so_ = RCPF(1.0f + EXP2(-(OG)));                                     \
    float tg_ = 2.0f * RCPF(1.0f + EXP2(-(GG))) - 1.0f;                       \
    float cn_ = sf_ * (CREF) + si_ * tg_;                                     \
    (CREF) = cn_;                                                             \
    float tc_ = 2.0f * RCPF(1.0f + EXP2(cn_ * NEG2L2E)) - 1.0f;               \
    float hv_ = so_ * tc_;                                                    \
    unsigned short hh_, hl_;                                                  \
    split2(hv_, hh_, hl_);                                                    \
    sh_hi[WRB][WIDX] = hh_;                                                   \
    sh_lo[WRB][WIDX] = hl_;                                                   \
  } while (0)

// ---------------------------------------------------------------------------
// Prep kernel: combine/prescale/split weights into ws.
// ---------------------------------------------------------------------------
__global__ void prep_weights(
    const float* __restrict__ Wih_c, const float* __restrict__ Whh_c,
    const float* __restrict__ bih_c, const float* __restrict__ bhh_c,
    const float* __restrict__ Wih_e, const float* __restrict__ Whh_e,
    const float* __restrict__ bih_e, const float* __restrict__ bhh_e,
    const float* __restrict__ Wih_d, const float* __restrict__ Whh_d,
    const float* __restrict__ bih_d, const float* __restrict__ bhh_d,
    const float* __restrict__ W_emb, const float* __restrict__ b_emb,
    unsigned short* __restrict__ wsu)
{
  int idx = blockIdx.x * 256 + threadIdx.x;
  float* wsf = (float*)(wsu + OFF_BIAS);
  unsigned short h, l;
  if (idx < 384 * 96) {
    int j = idx / 96;
    float s = (j >= 192 && j < 288) ? 2.0f * L2E : L2E;
    float w = (Wih_d[idx] + Whh_d[idx]) * s;
    split2(w, h, l);
    wsu[OFF_WD_HI + idx] = h; wsu[OFF_WD_LO + idx] = l;
  }
  if (idx < 256 * 96) {
    int j = idx / 96, k = idx - j * 96;
    float s = (j >= 128 && j < 192) ? 2.0f * L2E : L2E;
    float w = 0.0f;
    if (k < 64) w = Whh_e[j * 64 + k] * s;
    else if (k < 66) w = Wih_e[j * 2 + (k - 64)] * s;
    split2(w, h, l);
    wsu[OFF_WE_HI + idx] = h; wsu[OFF_WE_LO + idx] = l;
  }
  if (idx < 128 * 64) {
    int j = idx / 64, k = idx - j * 64;
    float s = (j >= 64 && j < 96) ? 2.0f * L2E : L2E;
    float w = 0.0f;
    if (k < 32) w = Whh_c[j * 32 + k] * s;
    else if (k < 34) w = Wih_c[j * 2 + (k - 32)] * s;
    split2(w, h, l);
    wsu[OFF_WC_HI + idx] = h; wsu[OFF_WC_LO + idx] = l;
  }
  if (idx < 16 * 96) {
    int n = idx / 96, k = idx - n * 96;
    float w = (n < 2) ? W_emb[n * 96 + k] : 0.0f;
    split2(w, h, l);
    wsu[OFF_WM_HI + idx] = h; wsu[OFF_WM_LO + idx] = l;
  }
  if (idx < 384) {
    float s = (idx >= 192 && idx < 288) ? 2.0f * L2E : L2E;
    wsf[idx] = (bih_d[idx] + bhh_d[idx]) * s;
  }
  if (idx < 256) {
    float s = (idx >= 128 && idx < 192) ? 2.0f * L2E : L2E;
    wsf[384 + idx] = (bih_e[idx] + bhh_e[idx]) * s;
  }
  if (idx < 128) {
    float s = (idx >= 64 && idx < 96) ? 2.0f * L2E : L2E;
    wsf[640 + idx] = (bih_c[idx] + bhh_c[idx]) * s;
  }
  if (idx < 2) wsf[768 + idx] = b_emb[idx];
}

// ---------------------------------------------------------------------------
// Main fused kernel. Block = 768 threads (12 waves), TB = 96 samples.
// ---------------------------------------------------------------------------
__global__ __launch_bounds__(768, 3) void lstm_fused(
    const float* __restrict__ traj,
    const float* __restrict__ ctr,
    const unsigned short* __restrict__ wsu,
    float* __restrict__ out)
{
  const int tid = threadIdx.x;
  const int wid = tid >> 6;
  const int lane = tid & 63;
  const int lr = lane & 15;
  const int lg = lane >> 4;
  const int blk = blockIdx.x;
  const bool xa = (lg == 0);

  const float* bias_d = (const float*)(wsu + OFF_BIAS);
  const float* bias_e = bias_d + 384;
  const float* bias_c = bias_d + 640;
  const float* bias_m = bias_d + 768;

  __shared__ __align__(16) unsigned short sh_hi[2][TB * S];   // 39,936 B
  __shared__ __align__(16) unsigned short sh_lo[2][TB * S];   // 39,936 B

  { // zero both h buffers (h0 = 0 for all phases)
    unsigned int* p0 = (unsigned int*)sh_hi;
    unsigned int* p1 = (unsigned int*)sh_lo;
    for (int i = tid; i < 2 * TB * S / 2; i += 768) { p0[i] = 0u; p1[i] = 0u; }
  }
  __syncthreads();

  // ================= centerline LSTM: H=32, T=100 (h cols 64..95) ==========
  // 12 tasks = 6 row-tiles x 2 unit-tiles, one per wave. Weights in registers.
  {
    const int ut = wid & 1;
    const int rg = wid >> 1;
    const int ucol = ut * 16 + lr;
    bf16x8 Bh_hi[4], Bh_lo[4], Bx_hi[4], Bx_lo[4];
    float bias[4];
#pragma unroll
    for (int g = 0; g < 4; ++g) {
      int j = g * 32 + ucol;
      Bh_hi[g] = *(const bf16x8*)(wsu + OFF_WC_HI + j * 64 + lg * 8);
      Bh_lo[g] = *(const bf16x8*)(wsu + OFF_WC_LO + j * 64 + lg * 8);
      Bx_hi[g] = *(const bf16x8*)(wsu + OFF_WC_HI + j * 64 + 32 + lg * 8);
      Bx_lo[g] = *(const bf16x8*)(wsu + OFF_WC_LO + j * 64 + 32 + lg * 8);
      bias[g] = bias_c[j];
    }
    float cr[4];
#pragma unroll
    for (int q = 0; q < 4; ++q) cr[q] = 0.0f;
    long srow = (long)blk * TB + rg * 16 + lr;
    if (srow > B_TOTAL - 1) srow = B_TOTAL - 1;
    const float* xrow = ctr + srow * 200;
    float4 xc = make_float4(0.f, 0.f, 0.f, 0.f);
    if (xa) xc = *(const float4*)xrow;

#define CENT_SUB(JP, X0, X1) do {                                             \
      const int rd_ = (JP), wr_ = (JP) ^ 1;                                   \
      bf16x8 Ax_hi = zero8(), Ax_lo = zero8();                                \
      if (xa) {                                                               \
        unsigned short h0_, l0_, h1_, l1_;                                    \
        split2((X0), h0_, l0_); split2((X1), h1_, l1_);                       \
        Ax_hi[0] = (short)h0_; Ax_hi[1] = (short)h1_;                         \
        Ax_lo[0] = (short)l0_; Ax_lo[1] = (short)l1_;                         \
      }                                                                       \
      bf16x8 Ah_hi = *(const bf16x8*)&sh_hi[rd_][(rg * 16 + lr) * S + 64 + lg * 8]; \
      bf16x8 Ah_lo = *(const bf16x8*)&sh_lo[rd_][(rg * 16 + lr) * S + 64 + lg * 8]; \
      f32x4 acc[4];                                                           \
      _Pragma("unroll")                                                       \
      for (int g = 0; g < 4; ++g) {                                           \
        f32x4 a = splat4(bias[g]);                                            \
        a = MFMA16(Ah_hi, Bh_hi[g], a);                                       \
        a = MFMA16(Ah_lo, Bh_hi[g], a);                                       \
        a = MFMA16(Ah_hi, Bh_lo[g], a);                                       \
        a = MFMA16(Ax_hi, Bx_hi[g], a);                                       \
        a = MFMA16(Ax_lo, Bx_hi[g], a);                                       \
        a = MFMA16(Ax_hi, Bx_lo[g], a);                                       \
        acc[g] = a;                                                           \
      }                                                                       \
      _Pragma("unroll")                                                       \
      for (int q = 0; q < 4; ++q) {                                           \
        ACTIVATE(acc[0][q], acc[1][q], acc[2][q], acc[3][q], cr[q],           \
                 (rg * 16 + lg * 4 + q) * S + 64 + ucol, wr_);                \
      }                                                                       \
      STEP_BARRIER();                                                         \
    } while (0)

    for (int gq = 0; gq < 50; ++gq) {        // steps t = 2gq, 2gq+1
      float4 xn = xc;
      if (xa && gq < 49) xn = *(const float4*)(xrow + 4 * (gq + 1));
      CENT_SUB(0, xc.x, xc.y);
      CENT_SUB(1, xc.z, xc.w);
      xc = xn;
    }
#undef CENT_SUB
    // t=99 wrote buf0 -> final cent h in buf0 cols 64..95.
    // Stash c (split bf16) in stale buf1 cols 64..95 (enc never touches them).
#pragma unroll
    for (int q = 0; q < 4; ++q) {
      unsigned short ch, cl;
      split2(cr[q], ch, cl);
      int r = rg * 16 + lg * 4 + q;
      sh_hi[1][r * S + 64 + ucol] = ch;
      sh_lo[1][r * S + 64 + ucol] = cl;
    }
  }
  __syncthreads();

  // ================= encoder LSTM: H=64, T=20 (h cols 0..63) ===============
  // 24 tasks = 6 row-tiles x 4 unit-tiles; wave w: ut=w&3, rts {w>>2, w>>2+3}.
  {
    const int ut = wid & 3;
    const int rb = wid >> 2;                 // rts rb, rb+3
    const int ucol = ut * 16 + lr;
    bf16x8 Bh_hi[4][2], Bx_hi[4];
    float bias[4];
#pragma unroll
    for (int g = 0; g < 4; ++g) {
      int j = g * 64 + ucol;
#pragma unroll
      for (int kb = 0; kb < 2; ++kb)
        Bh_hi[g][kb] = *(const bf16x8*)(wsu + OFF_WE_HI + j * 96 + kb * 32 + lg * 8);
      Bx_hi[g] = *(const bf16x8*)(wsu + OFF_WE_HI + j * 96 + 64 + lg * 8);
      bias[g] = bias_e[j];
    }
    float cr[2][4];
#pragma unroll
    for (int rt = 0; rt < 2; ++rt)
#pragma unroll
      for (int q = 0; q < 4; ++q) cr[rt][q] = 0.0f;
    long s0 = (long)blk * TB + rb * 16 + lr;       if (s0 > B_TOTAL - 1) s0 = B_TOTAL - 1;
    long s1 = (long)blk * TB + (rb + 3) * 16 + lr; if (s1 > B_TOTAL - 1) s1 = B_TOTAL - 1;
    const float* xr0 = traj + s0 * 40;
    const float* xr1 = traj + s1 * 40;
    float4 xc0 = make_float4(0.f, 0.f, 0.f, 0.f), xc1 = xc0;
    if (xa) { xc0 = *(const float4*)xr0; xc1 = *(const float4*)xr1; }

#define ENC_SUB(JP, X00, X01, X10, X11) do {                                  \
      const int rd_ = (JP), wr_ = (JP) ^ 1;                                   \
      int tofs = 0; asm volatile("" : "+v"(tofs));                            \
      bf16x8 Ax_hi[2], Ax_lo[2];                                              \
      Ax_hi[0] = zero8(); Ax_lo[0] = zero8();                                 \
      Ax_hi[1] = zero8(); Ax_lo[1] = zero8();                                 \
      if (xa) {                                                               \
        unsigned short h0_, l0_, h1_, l1_;                                    \
        split2((X00), h0_, l0_); split2((X01), h1_, l1_);                     \
        Ax_hi[0][0] = (short)h0_; Ax_hi[0][1] = (short)h1_;                   \
        Ax_lo[0][0] = (short)l0_; Ax_lo[0][1] = (short)l1_;                   \
        split2((X10), h0_, l0_); split2((X11), h1_, l1_);                     \
        Ax_hi[1][0] = (short)h0_; Ax_hi[1][1] = (short)h1_;                   \
        Ax_lo[1][0] = (short)l0_; Ax_lo[1][1] = (short)l1_;                   \
      }                                                                       \
      f32x4 acc[2][4];                                                        \
      _Pragma("unroll")                                                       \
      for (int rt = 0; rt < 2; ++rt)                                          \
        _Pragma("unroll")                                                     \
        for (int g = 0; g < 4; ++g) acc[rt][g] = splat4(bias[g]);             \
      _Pragma("unroll")                                                       \
      for (int kb = 0; kb < 2; ++kb) {                                        \
        bf16x8 ahi[2], alo[2];                                                \
        _Pragma("unroll")                                                     \
        for (int rt = 0; rt < 2; ++rt) {                                      \
          int rr = ((rb + 3 * rt) * 16 + lr) * S + kb * 32 + lg * 8;          \
          ahi[rt] = *(const bf16x8*)&sh_hi[rd_][rr];                          \
          alo[rt] = *(const bf16x8*)&sh_lo[rd_][rr];                          \
        }                                                                     \
        _Pragma("unroll")                                                     \
        for (int g = 0; g < 4; ++g) {                                         \
          int bo = (g * 64 + ucol) * 96 + kb * 32 + lg * 8 + tofs;            \
          bf16x8 blo = *(const bf16x8*)(wsu + OFF_WE_LO + bo);                \
          _Pragma("unroll")                                                   \
          for (int rt = 0; rt < 2; ++rt) {                                    \
            acc[rt][g] = MFMA16(ahi[rt], Bh_hi[g][kb], acc[rt][g]);           \
            acc[rt][g] = MFMA16(alo[rt], Bh_hi[g][kb], acc[rt][g]);           \
            acc[rt][g] = MFMA16(ahi[rt], blo, acc[rt][g]);                    \
          }                                                                   \
        }                                                                     \
      }                                                                       \
      _Pragma("unroll")                                                       \
      for (int g = 0; g < 4; ++g) {                                           \
        int bo = (g * 64 + ucol) * 96 + 64 + lg * 8 + tofs;                   \
        bf16x8 bxl = *(const bf16x8*)(wsu + OFF_WE_LO + bo);                  \
        _Pragma("unroll")                                                     \
        for (int rt = 0; rt < 2; ++rt) {                                      \
          acc[rt][g] = MFMA16(Ax_hi[rt], Bx_hi[g], acc[rt][g]);               \
          acc[rt][g] = MFMA16(Ax_lo[rt], Bx_hi[g], acc[rt][g]);               \
          acc[rt][g] = MFMA16(Ax_hi[rt], bxl, acc[rt][g]);                    \
        }                                                                     \
      }                                                                       \
      _Pragma("unroll")                                                       \
      for (int rt = 0; rt < 2; ++rt)                                          \
        _Pragma("unroll")                                                     \
        for (int q = 0; q < 4; ++q) {                                         \
          ACTIVATE(acc[rt][0][q], acc[rt][1][q], acc[rt][2][q], acc[rt][3][q],\
                   cr[rt][q],                                                 \
                   ((rb + 3 * rt) * 16 + lg * 4 + q) * S + ucol, wr_);        \
        }                                                                     \
      STEP_BARRIER();                                                         \
    } while (0)

    for (int gq = 0; gq < 10; ++gq) {        // steps t = 2gq, 2gq+1
      float4 xn0 = xc0, xn1 = xc1;
      if (xa && gq < 9) {
        xn0 = *(const float4*)(xr0 + 4 * (gq + 1));
        xn1 = *(const float4*)(xr1 + 4 * (gq + 1));
      }
      ENC_SUB(0, xc0.x, xc0.y, xc1.x, xc1.y);
      ENC_SUB(1, xc0.z, xc0.w, xc1.z, xc1.w);
      xc0 = xn0; xc1 = xn1;
    }
#undef ENC_SUB
    // t=19 wrote buf0 -> buf0 = [enc_h | cent_h] = decoder h0.
    // Stash enc c (split bf16) in stale buf1 cols 0..63.
#pragma unroll
    for (int rt = 0; rt < 2; ++rt)
#pragma unroll
      for (int q = 0; q < 4; ++q) {
        unsigned short ch, cl;
        split2(cr[rt][q], ch, cl);
        int r = (rb + 3 * rt) * 16 + lg * 4 + q;
        sh_hi[1][r * S + ucol] = ch;
        sh_lo[1][r * S + ucol] = cl;
      }
  }
  __syncthreads();

  // ================= decoder LSTM: H=96, T=30 + projection =================
  // 36 tasks = 6 row-tiles x 6 unit-tiles; wave w: ut=w%6, rts {rh,rh+2,rh+4}.
  {
    const int ut = wid % 6;
    const int rh = wid / 6;                  // 0 or 1
    const int ucol = ut * 16 + lr;
    bf16x8 Bh_hi[4][3];
    float bias[4];
#pragma unroll
    for (int g = 0; g < 4; ++g) {
      int j = g * 96 + ucol;
#pragma unroll
      for (int kb = 0; kb < 3; ++kb)
        Bh_hi[g][kb] = *(const bf16x8*)(wsu + OFF_WD_HI + j * 96 + kb * 32 + lg * 8);
      bias[g] = bias_d[j];
    }
    float pbias = (lr < 2) ? bias_m[lr] : 0.0f;
    float cr[3][4];
#pragma unroll
    for (int rt = 0; rt < 3; ++rt)           // c0 = [c_enc | c_cent] from buf1 stash
#pragma unroll
      for (int q = 0; q < 4; ++q) {
        int r = ((rh + 2 * rt) * 16 + lg * 4 + q) * S + ucol;
        unsigned int ch = sh_hi[1][r];
        unsigned int cl = sh_lo[1][r];
        cr[rt][q] = __uint_as_float(ch << 16) + __uint_as_float(cl << 16);
      }

#define DEC_SUB(JP, TT) do {                                                  \
      const int rd_ = (JP), wr_ = (JP) ^ 1;                                   \
      int tofs = 0; asm volatile("" : "+v"(tofs));                            \
      f32x4 acc[3][4];                                                        \
      _Pragma("unroll")                                                       \
      for (int rt = 0; rt < 3; ++rt)                                          \
        _Pragma("unroll")                                                     \
        for (int g = 0; g < 4; ++g) acc[rt][g] = splat4(bias[g]);             \
      _Pragma("unroll")                                                       \
      for (int kb = 0; kb < 3; ++kb) {                                        \
        bf16x8 ahi[3], alo[3];                                                \
        _Pragma("unroll")                                                     \
        for (int rt = 0; rt < 3; ++rt) {                                      \
          int rr = ((rh + 2 * rt) * 16 + lr) * S + kb * 32 + lg * 8;          \
          ahi[rt] = *(const bf16x8*)&sh_hi[rd_][rr];                          \
          alo[rt] = *(const bf16x8*)&sh_lo[rd_][rr];                          \
        }                                                                     \
        _Pragma("unroll")                                                     \
        for (int g = 0; g < 4; ++g) {                                         \
          int bo = (g * 96 + ucol) * 96 + kb * 32 + lg * 8 + tofs;            \
          bf16x8 blo = *(const bf16x8*)(wsu + OFF_WD_LO + bo);                \
          _Pragma("unroll")                                                   \
          for (int rt = 0; rt < 3; ++rt) {                                    \
            acc[rt][g] = MFMA16(ahi[rt], Bh_hi[g][kb], acc[rt][g]);           \
            acc[rt][g] = MFMA16(alo[rt], Bh_hi[g][kb], acc[rt][g]);           \
            acc[rt][g] = MFMA16(ahi[rt], blo, acc[rt][g]);                    \
          }                                                                   \
        }                                                                     \
      }                                                                       \
      _Pragma("unroll")                                                       \
      for (int rt = 0; rt < 3; ++rt)                                          \
        _Pragma("unroll")                                                     \
        for (int q = 0; q < 4; ++q) {                                         \
          ACTIVATE(acc[rt][0][q], acc[rt][1][q], acc[rt][2][q], acc[rt][3][q],\
                   cr[rt][q],                                                 \
                   ((rh + 2 * rt) * 16 + lg * 4 + q) * S + ucol, wr_);        \
        }                                                                     \
      STEP_BARRIER();                                                         \
      if (wid < 6) {                                                          \
        f32x4 ap = splat4(pbias);                                             \
        _Pragma("unroll")                                                     \
        for (int kb = 0; kb < 3; ++kb) {                                      \
          int rr = (wid * 16 + lr) * S + kb * 32 + lg * 8;                    \
          bf16x8 phh = *(const bf16x8*)&sh_hi[wr_][rr];                       \
          bf16x8 pll = *(const bf16x8*)&sh_lo[wr_][rr];                       \
          int mo = lr * 96 + kb * 32 + lg * 8 + tofs;                         \
          bf16x8 bmh = *(const bf16x8*)(wsu + OFF_WM_HI + mo);                \
          bf16x8 bml = *(const bf16x8*)(wsu + OFF_WM_LO + mo);                \
          ap = MFMA16(phh, bmh, ap);                                          \
          ap = MFMA16(pll, bmh, ap);                                          \
          ap = MFMA16(phh, bml, ap);                                          \
        }                                                                     \
        if (lr < 2) {                                                         \
          _Pragma("unroll")                                                   \
          for (int q = 0; q < 4; ++q) {                                       \
            long s = (long)blk * TB + wid * 16 + lg * 4 + q;                  \
            if (s < B_TOTAL) out[s * 60 + (TT) * 2 + lr] = ap[q];             \
          }                                                                   \
        }                                                                     \
      }                                                                       \
    } while (0)

    for (int it = 0; it < 15; ++it) {        // steps t = 2it, 2it+1
      DEC_SUB(0, 2 * it);
      DEC_SUB(1, 2 * it + 1);
    }
#undef DEC_SUB
  }
}

extern "C" void kernel_launch(void* const* d_in, const int* in_sizes, int n_in,
                              void* d_out, int out_size, void* d_ws, size_t ws_size,
                              hipStream_t stream)
{
  if (ws_size < 287752) return;   // need ~288 KB of scratch for prepped weights
  const float* traj = (const float*)d_in[0];
  const float* ctr  = (const float*)d_in[1];
  prep_weights<<<144, 256, 0, stream>>>(
      (const float*)d_in[2],  (const float*)d_in[3],  (const float*)d_in[4],  (const float*)d_in[5],
      (const float*)d_in[6],  (const float*)d_in[7],  (const float*)d_in[8],  (const float*)d_in[9],
      (const float*)d_in[10], (const float*)d_in[11], (const float*)d_in[12], (const float*)d_in[13],
      (const float*)d_in[14], (const float*)d_in[15],
      (unsigned short*)d_ws);
  lstm_fused<<<NBLK, 768, 0, stream>>>(traj, ctr, (const unsigned short*)d_ws, (float*)d_out);
}